// Round 1
// 477.718 us; speedup vs baseline: 1.2965x; 1.2965x over previous
//
#include <hip/hip_runtime.h>
#include <hip/hip_bf16.h>

#define N_NODES 100000
#define N_EDGES 600000
#define HD 128
#define NBC 384
#define SCAN_B 98   // ceil(N_NODES/1024)
#define MAXFIX 4096
#define TILES ((N_NODES + 63) / 64)  // 1563
#define GRID_F 512
#define AGG_B (N_NODES / 4)          // 25000

typedef __attribute__((ext_vector_type(8))) short s8v;
typedef __attribute__((ext_vector_type(4))) short s4v;
typedef __attribute__((ext_vector_type(4))) float f4v;
typedef __hip_bfloat16 bf16;

static __device__ __forceinline__ float bf2f(bf16 v) { return __bfloat162float(v); }
static __device__ __forceinline__ bf16 f2bf(float v) { return __float2bfloat16(v); }
static __device__ __forceinline__ float sh2f(short s) { bf16 h = *(bf16*)&s; return bf2f(h); }
static __device__ __forceinline__ float ldraw(const void* p, int i, int fp32) {
    return fp32 ? ((const float*)p)[i] : bf2f(((const bf16*)p)[i]);
}

// async global->LDS, 16B per lane; lds dest = wave-uniform base + lane*16
static __device__ __forceinline__ void gl2lds16(const void* g, void* l) {
    __builtin_amdgcn_global_load_lds(
        (const __attribute__((address_space(1))) void*)g,
        (__attribute__((address_space(3))) void*)l, 16, 0, 0);
}

// ================= K1: dtype detect (wave-parallel) + zero deg/ccount/n0cnt ======
__global__ void k_init(const unsigned short* __restrict__ wraw, const int* __restrict__ eraw,
                       int* __restrict__ flags, int* __restrict__ deg,
                       int* __restrict__ ccount, int* __restrict__ n0cnt) {
    int b = blockIdx.x, t = threadIdx.x;
    if (b == 0) {
        if (t < 64) {
            int bad = 0;
            for (int k = 0; k < 16; k++) {
                unsigned int u = ((unsigned int)wraw[t * 16 + k]) << 16;
                float f = fabsf(__uint_as_float(u));
                if (!(f <= 1e4f)) bad = 1;  // catches huge AND NaN
            }
            unsigned long long m = __ballot(bad);
            if (t == 0) {
                flags[0] = m ? 1 : 0;
                flags[1] = (eraw[1] == 0 && eraw[3] == 0 && eraw[5] == 0 && eraw[7] == 0) ? 1 : 0;
            }
        }
    } else if (b <= 98) {
        int i = (b - 1) * 256 + t;
        if (i < 25000) ((int4*)deg)[i] = make_int4(0, 0, 0, 0);   // 100000 ints
    } else {
        if (t < 96) ((int4*)ccount)[t] = make_int4(0, 0, 0, 0);   // 384 ints
        if (t == 96) *n0cnt = 0;
    }
}

// ===== K2: mega conversion + counts + composed-weight prep (heavy blocks first) ==
#define KB_J 192              // Wc compose
#define KB_K (KB_J + 32)      // 224  Wet
#define KB_L (KB_K + 1)       // 225  bc + bcenc
#define KB_A (KB_L + 5860)    // 6085 cf
#define KB_B (KB_A + 391)     // 6476 slf
#define KB_C (KB_B + 12500)   // 18976 z
#define KB_D (KB_C + 782)     // 19758 xin pad zero
#define KB_E (KB_D + 2)       // 19760 tr
#define KB_F (KB_E + 192)     // 19952 Wu -> Wuc
#define KB_G (KB_F + 1)       // 19953 bu -> buc
#define KB_H (KB_G + 4688)    // 24641 e cvt + deg count
#define KB_I (KB_H + 391)     // 25032 cc cvt + cluster count
__global__ void k_mega(const int* __restrict__ flags,
                       const void* cf_r, const void* slf_r, const void* z_r,
                       const void* tr_r, const void* Wenc_r, const void* benc_r,
                       const void* Wm_r, const void* bm_r, const void* Wu_r,
                       const void* bu_r, const int* __restrict__ e_r,
                       const int* __restrict__ cc_r,
                       bf16* __restrict__ xin, bf16* __restrict__ trc,
                       bf16* __restrict__ Wuc, bf16* __restrict__ buc,
                       int* __restrict__ ec, int* __restrict__ ccc,
                       int* __restrict__ deg, int* __restrict__ ccount,
                       bf16* __restrict__ Wc, float* __restrict__ bc,
                       bf16* __restrict__ Wet, float* __restrict__ bcenc) {
    int b = blockIdx.x, t = threadIdx.x;
    int fp32 = flags[0];
    if (b < KB_J) {           // compose Wc from RAW Wm/Wu (flag-dispatched loads)
        int i = b * 256 + t;  // < 49152
        int w = i / 384, kk = i - w * 384;
        float acc = 0.f;
        if (kk < 128) {
            acc = ldraw(Wu_r, kk * 128 + w, fp32);
            for (int j = 0; j < 128; j++)
                acc += ldraw(Wm_r, kk * 128 + j, fp32) * ldraw(Wu_r, (128 + j) * 128 + w, fp32);
        } else if (kk < 256) {
            int kp = kk - 128;
            for (int j = 0; j < 128; j++)
                acc += ldraw(Wm_r, (128 + kp) * 128 + j, fp32) * ldraw(Wu_r, (128 + j) * 128 + w, fp32);
        } else {
            acc = ldraw(Wu_r, kk * 128 + w, fp32);
        }
        Wc[w * 384 + kk] = f2bf(acc);
    } else if (b < KB_K) {    // Wet: transposed, zero-padded encoder weight
        int i = (b - KB_J) * 256 + t;  // < 8192
        int w = i >> 6, kk = i & 63;
        float v = (kk < 48) ? ldraw(Wenc_r, kk * 128 + w, fp32) : 0.f;
        Wet[i] = f2bf(v);
    } else if (b < KB_L) {    // bc compose + bcenc
        if (t < 128) {
            float acc = ldraw(bu_r, t, fp32);
            for (int j = 0; j < 128; j++)
                acc += ldraw(bm_r, j, fp32) * ldraw(Wu_r, (128 + j) * 128 + t, fp32);
            bc[t] = acc;
        } else if (t < 256) {
            bcenc[t - 128] = ldraw(benc_r, t - 128, fp32);
        }
    } else if (b < KB_A) {    // cf -> xin cols 0..14
        int i = (b - KB_L) * 256 + t;
        if (i < 1500000) {
            int node = i / 15;
            xin[(size_t)node * 64 + (i - node * 15)] = f2bf(ldraw(cf_r, i, fp32));
        }
    } else if (b < KB_B) {    // slf -> col 15
        int i = (b - KB_A) * 256 + t;
        if (i < 100000) xin[(size_t)i * 64 + 15] = f2bf(ldraw(slf_r, i, fp32));
    } else if (b < KB_C) {    // z -> cols 16..47
        int i = (b - KB_B) * 256 + t;
        if (i < 3200000) xin[(size_t)(i >> 5) * 64 + 16 + (i & 31)] = f2bf(ldraw(z_r, i, fp32));
    } else if (b < KB_D) {    // pad cols 48..63 zero (replaces 12.8MB memset)
        int p = (b - KB_C) * 2048 + t * 8;
        if (p < 1600000) {
            int row = p >> 4, off = p & 15;  // off in {0,8}
            s8v zz = {0, 0, 0, 0, 0, 0, 0, 0};
            *(s8v*)((short*)xin + (size_t)row * 64 + 48 + off) = zz;
        }
    } else if (b < KB_E) {    // tr -> trc
        int i = (b - KB_D) * 256 + t;
        if (i < 384) trc[i] = f2bf(ldraw(tr_r, i, fp32));
    } else if (b < KB_F) {    // Wu -> Wuc (for deg-0 fixup)
        int i = (b - KB_E) * 256 + t;  // < 49152 exact
        Wuc[i] = f2bf(ldraw(Wu_r, i, fp32));
    } else if (b < KB_G) {    // bu -> buc
        if (t < 128) buc[t] = f2bf(ldraw(bu_r, t, fp32));
    } else if (b < KB_H) {    // e cvt + degree count fused
        int i64f = flags[1];
        int i = (b - KB_G) * 256 + t;
        if (i < 2 * N_EDGES) {
            int v = i64f ? e_r[2 * i] : e_r[i];
            ec[i] = v;
            if (i >= N_EDGES) atomicAdd(&deg[v], 1);
        }
    } else {                  // cc cvt + cluster count fused
        int i64f = flags[1];
        int i = (b - KB_H) * 256 + t;
        if (i < N_NODES) {
            int v = i64f ? cc_r[2 * i] : cc_r[i];
            ccc[i] = v;
            atomicAdd(&ccount[v], 1);
        }
    }
}

// ====== K3: per-block scan of deg (blocks 0..97) + cluster exclusive scan (98) ===
__global__ void k_scan_a2(const int* __restrict__ deg, int* __restrict__ rowptr,
                          int* __restrict__ bsum, const int* __restrict__ ccount,
                          int* __restrict__ coff, int* __restrict__ ccur) {
    __shared__ int sd[1024];
    int t = threadIdx.x;
    if (blockIdx.x < SCAN_B) {
        int i = blockIdx.x * 1024 + t;
        int v = (i < N_NODES) ? deg[i] : 0;
        sd[t] = v;
        __syncthreads();
#pragma unroll
        for (int off = 1; off < 1024; off <<= 1) {
            int u = (t >= off) ? sd[t - off] : 0;
            __syncthreads();
            sd[t] += u;
            __syncthreads();
        }
        if (i < N_NODES) rowptr[i] = sd[t] - v;
        if (t == 1023) bsum[blockIdx.x] = sd[t];
    } else {
        int v = (t < NBC) ? ccount[t] : 0;
        sd[t] = v;
        __syncthreads();
#pragma unroll
        for (int off = 1; off < 1024; off <<= 1) {
            int u = (t >= off) ? sd[t - off] : 0;
            __syncthreads();
            sd[t] += u;
            __syncthreads();
        }
        if (t < NBC) {
            int ex = sd[t] - v;
            coff[t] = ex;
            ccur[t] = ex;
            if (t == NBC - 1) coff[NBC] = sd[t];
        }
    }
}

// ====== K4: apply block offsets (each block sums bsum prefix itself; no scan_b) ==
__global__ void k_scan_c2(int* __restrict__ rowptr, int* __restrict__ cursor,
                          const int* __restrict__ bsum) {
    __shared__ int sb[128];
    __shared__ int offs;
    int b = blockIdx.x, t = threadIdx.x;
    if (t < 128) sb[t] = (t < b) ? bsum[t] : 0;   // b <= 97 < 128
    __syncthreads();
    if (t == 0) {
        int s = 0;
        for (int k = 0; k < 128; k++) s += sb[k];
        offs = s;
    }
    __syncthreads();
    int i = b * 1024 + t;
    if (i < N_NODES) {
        int r = rowptr[i] + offs;
        rowptr[i] = r;
        cursor[i] = r;
    }
    if (b == 0 && t == 0) rowptr[N_NODES] = N_EDGES;
}

// ====== K5: encoder MFMA + CSR fills + deg-0 list, one launch (block-split) ======
#define K5_EN 1563
#define K5_FE (K5_EN + 2344)   // 3907
#define K5_FN (K5_FE + 391)    // 4298
#define K5_L0 (K5_FN + 391)    // 4689
__global__ void k_front(const bf16* __restrict__ xin, const bf16* __restrict__ Wet,
                        const float* __restrict__ bcenc, bf16* __restrict__ xb,
                        const int* __restrict__ ec, int* __restrict__ cursor,
                        int* __restrict__ colx, const int* __restrict__ ccc,
                        int* __restrict__ ccur, int* __restrict__ cnodes,
                        const int* __restrict__ deg, int* __restrict__ n0list,
                        int* __restrict__ n0cnt) {
    int b = blockIdx.x;
    if (b >= K5_EN) {
        if (b < K5_FE) {          // fill edges (CSR col)
            int i = (b - K5_EN) * 256 + threadIdx.x;
            if (i < N_EDGES) {
                int d = ec[N_EDGES + i];
                int p = atomicAdd(&cursor[d], 1);
                colx[p] = ec[i];
            }
        } else if (b < K5_FN) {   // fill cluster node lists
            int i = (b - K5_FE) * 256 + threadIdx.x;
            if (i < N_NODES) {
                int p = atomicAdd(&ccur[ccc[i]], 1);
                cnodes[p] = i;
            }
        } else {                  // deg-0 list
            int i = (b - K5_FN) * 256 + threadIdx.x;
            if (i < N_NODES && deg[i] == 0) {
                int p = atomicAdd(n0cnt, 1);
                if (p < MAXFIX) n0list[p] = i;
            }
        }
        return;
    }
    // ---- MFMA encoder: xb = bf16( xin[N,64] @ Wet^T + benc ) ----
    int tid = threadIdx.x;
    int r0 = b * 64;
    int wave = tid >> 6, lane = tid & 63, quad = lane >> 4, nidx = lane & 15;
    int colbase = wave * 32;

    int arow[4];
#pragma unroll
    for (int rt = 0; rt < 4; rt++) {
        int gr = r0 + rt * 16 + nidx;
        arow[rt] = (gr < N_NODES) ? gr : (N_NODES - 1);
    }
    f4v acc[4][2];
#pragma unroll
    for (int rt = 0; rt < 4; rt++)
#pragma unroll
        for (int ct = 0; ct < 2; ct++) acc[rt][ct] = (f4v){0.f, 0.f, 0.f, 0.f};

#pragma unroll
    for (int s = 0; s < 2; s++) {
        int k0 = s * 32;
        s8v bfrag[4];
#pragma unroll
        for (int rt = 0; rt < 4; rt++)
            bfrag[rt] = *(const s8v*)((const short*)xin + (size_t)arow[rt] * 64 + k0 + quad * 8);
#pragma unroll
        for (int ct = 0; ct < 2; ct++) {
            s8v wfr = *(const s8v*)((const short*)Wet + (colbase + ct * 16 + nidx) * 64 + k0 + quad * 8);
#pragma unroll
            for (int rt = 0; rt < 4; rt++)
                acc[rt][ct] = __builtin_amdgcn_mfma_f32_16x16x32_bf16(wfr, bfrag[rt], acc[rt][ct], 0, 0, 0);
        }
    }
#pragma unroll
    for (int rt = 0; rt < 4; rt++) {
        int gr = r0 + rt * 16 + nidx;
        if (gr < N_NODES) {
#pragma unroll
            for (int ct = 0; ct < 2; ct++) {
                int wc0 = colbase + ct * 16 + quad * 4;
                f4v bv = *(const f4v*)(bcenc + wc0);
                size_t idx = (size_t)gr * HD + wc0;
                s4v ob;
#pragma unroll
                for (int r = 0; r < 4; r++) {
                    float nv = acc[rt][ct][r] + bv[r];
                    bf16 h = f2bf(nv);
                    ob[r] = *(short*)&h;
                }
                *(s4v*)((short*)xb + idx) = ob;
            }
        }
    }
}

// ====== K6 (per layer): cluster pooling (blocks 0..383) + edge aggregation =======
// Pool: one block per cluster, 8 node-slots x 32 col-groups, s4v (8B) loads,
// fp32 accumulate, LDS reduce, no atomics, no memset.
__global__ void k_aggpool(const bf16* __restrict__ xb, const int* __restrict__ rowptr,
                          const int* __restrict__ colx, bf16* __restrict__ mb,
                          const int* __restrict__ coff, const int* __restrict__ cnodes,
                          const bf16* __restrict__ trc, bf16* __restrict__ pooled) {
    __shared__ float red[8][128];
    int tid = threadIdx.x;
    if (blockIdx.x < NBC) {
        int cl = blockIdx.x;
        int lo = coff[cl], hi = coff[cl + 1];
        int cnt = hi - lo;
        int slot = tid >> 5, cg = tid & 31;
        float a0 = 0.f, a1 = 0.f, a2 = 0.f, a3 = 0.f;
        for (int i = lo + slot; i < hi; i += 8) {
            int nd = cnodes[i];
            s4v v = *(const s4v*)((const short*)xb + (size_t)nd * HD + cg * 4);
            a0 += sh2f(v[0]); a1 += sh2f(v[1]); a2 += sh2f(v[2]); a3 += sh2f(v[3]);
        }
        red[slot][cg * 4 + 0] = a0;
        red[slot][cg * 4 + 1] = a1;
        red[slot][cg * 4 + 2] = a2;
        red[slot][cg * 4 + 3] = a3;
        __syncthreads();
        if (tid < 128) {
            float s = 0.f;
#pragma unroll
            for (int k = 0; k < 8; k++) s += red[k][tid];
            float v = s / (float)(cnt > 1 ? cnt : 1) * bf2f(trc[cl]);
            pooled[cl * HD + tid] = f2bf(v);
        }
        return;
    }
    // ---- aggregation: mean of x[src] over incoming edges ----
    int wave = tid >> 6, lane = tid & 63;
    int node = (blockIdx.x - NBC) * 4 + wave;
    if (node >= N_NODES) return;
    int half = lane >> 5;
    int l = lane & 31;
    int lo = rowptr[node], hi = rowptr[node + 1];
    float a0 = 0.f, a1 = 0.f, a2 = 0.f, a3 = 0.f;
    int j = lo + half;
    while (j + 2 < hi) {
        int s0 = colx[j], s1 = colx[j + 2];
        s4v v0 = *(const s4v*)((const short*)xb + (size_t)s0 * HD + l * 4);
        s4v v1 = *(const s4v*)((const short*)xb + (size_t)s1 * HD + l * 4);
        a0 += sh2f(v0[0]) + sh2f(v1[0]);
        a1 += sh2f(v0[1]) + sh2f(v1[1]);
        a2 += sh2f(v0[2]) + sh2f(v1[2]);
        a3 += sh2f(v0[3]) + sh2f(v1[3]);
        j += 4;
    }
    if (j < hi) {
        int s0 = colx[j];
        s4v v0 = *(const s4v*)((const short*)xb + (size_t)s0 * HD + l * 4);
        a0 += sh2f(v0[0]);
        a1 += sh2f(v0[1]);
        a2 += sh2f(v0[2]);
        a3 += sh2f(v0[3]);
    }
    a0 += __shfl_down(a0, 32);
    a1 += __shfl_down(a1, 32);
    a2 += __shfl_down(a2, 32);
    a3 += __shfl_down(a3, 32);
    if (half == 0) {
        int d = hi - lo;
        float inv = 1.0f / (float)(d > 1 ? d : 1);
        s4v o;
        bf16 h0 = f2bf(a0 * inv); o[0] = *(short*)&h0;
        bf16 h1 = f2bf(a1 * inv); o[1] = *(short*)&h1;
        bf16 h2 = f2bf(a2 * inv); o[2] = *(short*)&h2;
        bf16 h3 = f2bf(a3 * inv); o[3] = *(short*)&h3;
        *(s4v*)((short*)mb + (size_t)node * HD + l * 4) = o;
    }
}

// ====== K7 (per layer): fused update (persistent, LDS-staged) + deg-0 fixup ======
__global__ __launch_bounds__(256, 2) void k_fused2(
    const bf16* __restrict__ xb, const bf16* __restrict__ mb, const bf16* __restrict__ pooled,
    const bf16* __restrict__ Wc, const float* __restrict__ bc,
    const int* __restrict__ cc, const int* __restrict__ deg,
    const bf16* __restrict__ Wuc, const bf16* __restrict__ buc,
    const int* __restrict__ n0list, const int* __restrict__ n0cnt,
    bf16* __restrict__ xbo, const int* __restrict__ flags,
    void* __restrict__ out, int last) {
    __shared__ short Lx[64 * 128];
    __shared__ short Lm[64 * 128];
    __shared__ short Lp[64 * 128];
    __shared__ float fxv[128];
    __shared__ float fpv[128];
    int tid = threadIdx.x;
    int wave = tid >> 6, lane = tid & 63, quad = lane >> 4, nidx = lane & 15;
    int colbase = wave * 32;
    int fp32out = flags[0];

    s8v wfr[12][2];
#pragma unroll
    for (int ct = 0; ct < 2; ct++) {
        int wcol = colbase + ((nidx >> 2) << 3) + ct * 4 + (nidx & 3);
        const short* wrow = (const short*)Wc + (size_t)wcol * 384 + quad * 8;
#pragma unroll
        for (int s = 0; s < 12; s++) wfr[s][ct] = *(const s8v*)(wrow + s * 32);
    }
    int cb2 = colbase + quad * 8;
    f4v bv0 = *(const f4v*)(bc + cb2);
    f4v bv1 = *(const f4v*)(bc + cb2 + 4);

    int srow = lane >> 4;
    int sc = lane & 15;

    for (int t = blockIdx.x; t < TILES; t += GRID_F) {
        int r0 = t * 64;
#pragma unroll
        for (int ii = 0; ii < 4; ii++) {
            int i = wave * 4 + ii;
            int lr = i * 4 + srow;
            int gr = r0 + lr;
            int grc = (gr < N_NODES) ? gr : (N_NODES - 1);
            int gc = sc ^ (lr & 15);
            gl2lds16((const short*)xb + (size_t)grc * HD + gc * 8, (char*)Lx + i * 1024);
            gl2lds16((const short*)mb + (size_t)grc * HD + gc * 8, (char*)Lm + i * 1024);
            int ci = cc[grc];
            gl2lds16((const short*)pooled + (size_t)ci * HD + gc * 8, (char*)Lp + i * 1024);
        }
        __syncthreads();

        f4v acc[4][2];
#pragma unroll
        for (int rt = 0; rt < 4; rt++)
#pragma unroll
            for (int ct = 0; ct < 2; ct++) acc[rt][ct] = (f4v){0.f, 0.f, 0.f, 0.f};

#pragma unroll
        for (int s = 0; s < 12; s++) {
            const short* Ls = (s < 4) ? Lx : ((s < 8) ? Lm : Lp);
            int c = (s & 3) * 4 + quad;
            s8v bfrag[4];
#pragma unroll
            for (int rt = 0; rt < 4; rt++) {
                int row = rt * 16 + nidx;
                int slot = c ^ nidx;
                bfrag[rt] = *(const s8v*)(Ls + row * 128 + slot * 8);
            }
#pragma unroll
            for (int ct = 0; ct < 2; ct++)
#pragma unroll
                for (int rt = 0; rt < 4; rt++)
                    acc[rt][ct] = __builtin_amdgcn_mfma_f32_16x16x32_bf16(wfr[s][ct], bfrag[rt], acc[rt][ct], 0, 0, 0);
        }

#pragma unroll
        for (int rt = 0; rt < 4; rt++) {
            int gr = r0 + rt * 16 + nidx;
            if (gr < N_NODES && deg[gr] > 0) {
                int row = rt * 16 + nidx;
                int slot = ((colbase >> 3) + quad) ^ nidx;
                s8v xo = *(const s8v*)(Lx + row * 128 + slot * 8);
                size_t idx = (size_t)gr * HD + cb2;
                float nv[8];
#pragma unroll
                for (int r = 0; r < 4; r++) {
                    float v0 = acc[rt][0][r] + bv0[r];
                    v0 = (v0 > 0.f) ? v0 : 0.01f * v0;
                    nv[r] = sh2f(xo[r]) + v0;
                    float v1 = acc[rt][1][r] + bv1[r];
                    v1 = (v1 > 0.f) ? v1 : 0.01f * v1;
                    nv[4 + r] = sh2f(xo[4 + r]) + v1;
                }
                if (last) {
                    if (fp32out) {
                        f4v o0 = {nv[0], nv[1], nv[2], nv[3]};
                        f4v o1 = {nv[4], nv[5], nv[6], nv[7]};
                        *(f4v*)((float*)out + idx) = o0;
                        *(f4v*)((float*)out + idx + 4) = o1;
                    } else {
                        s8v ob;
#pragma unroll
                        for (int r = 0; r < 8; r++) { bf16 h = f2bf(nv[r]); ob[r] = *(short*)&h; }
                        *(s8v*)((short*)out + idx) = ob;
                    }
                } else {
                    s8v ob;
#pragma unroll
                    for (int r = 0; r < 8; r++) { bf16 h = f2bf(nv[r]); ob[r] = *(short*)&h; }
                    *(s8v*)((short*)xbo + idx) = ob;
                }
            }
        }
        __syncthreads();
    }

    // ---- deg-0 fixup tail (disjoint rows; fused2 skipped deg==0) ----
    int cnt0 = *n0cnt;
    if (cnt0 > MAXFIX) cnt0 = MAXFIX;
    for (int j = blockIdx.x; j < cnt0; j += gridDim.x) {
        int v = n0list[j];
        if (tid < 128) {
            fxv[tid] = bf2f(xb[(size_t)v * HD + tid]);
            fpv[tid] = bf2f(pooled[cc[v] * HD + tid]);
        }
        __syncthreads();
        if (tid < 128) {
            float acc = bf2f(buc[tid]);
            for (int k = 0; k < 128; k++)
                acc += fxv[k] * bf2f(Wuc[k * 128 + tid]) + fpv[k] * bf2f(Wuc[(256 + k) * 128 + tid]);
            float u = acc > 0.f ? acc : 0.01f * acc;
            size_t idx = (size_t)v * HD + tid;
            float nv = fxv[tid] + u;
            if (last) {
                if (fp32out) ((float*)out)[idx] = nv;
                else ((bf16*)out)[idx] = f2bf(nv);
            } else {
                xbo[idx] = f2bf(nv);
            }
        }
        __syncthreads();
    }
}

extern "C" void kernel_launch(void* const* d_in, const int* in_sizes, int n_in,
                              void* d_out, int out_size, void* d_ws, size_t ws_size,
                              hipStream_t stream) {
    const void* cf_r = d_in[0];
    const void* slf_r = d_in[1];
    const void* z_r = d_in[2];
    const void* tr_r = d_in[3];
    const void* Wenc_r = d_in[4];
    const void* benc_r = d_in[5];
    const void* Wm_r = d_in[6];
    const void* bm_r = d_in[7];
    const void* Wu_r = d_in[8];
    const void* bu_r = d_in[9];
    const int* e_r = (const int*)d_in[10];
    const int* cc_r = (const int*)d_in[11];

    char* w = (char*)d_ws;
    auto alloc = [&](size_t bytes) -> char* {
        char* p = w;
        w += (bytes + 63) & ~(size_t)63;
        return p;
    };
    bf16* xb0 = (bf16*)alloc((size_t)N_NODES * HD * 2);
    bf16* xb1 = (bf16*)alloc((size_t)N_NODES * HD * 2);
    bf16* mb = (bf16*)alloc((size_t)N_NODES * HD * 2);
    bf16* xin = (bf16*)alloc((size_t)N_NODES * 64 * 2);
    bf16* Wc = (bf16*)alloc(128 * 384 * 2);
    float* bc = (float*)alloc(128 * 4);
    bf16* Wet = (bf16*)alloc(128 * 64 * 2);
    float* bcenc = (float*)alloc(128 * 4);
    bf16* pooled = (bf16*)alloc(NBC * HD * 2);
    int* deg = (int*)alloc(N_NODES * 4);
    int* rowptr = (int*)alloc((N_NODES + 1) * 4);
    int* cursor = (int*)alloc(N_NODES * 4);
    int* colx = (int*)alloc(N_EDGES * 4);
    int* ccount = (int*)alloc(NBC * 4);
    int* coff = (int*)alloc((NBC + 1) * 4);
    int* ccur = (int*)alloc(NBC * 4);
    int* cnodes = (int*)alloc(N_NODES * 4);
    int* flags = (int*)alloc(64);
    int* bsum = (int*)alloc(SCAN_B * 4);
    int* n0list = (int*)alloc(MAXFIX * 4);
    int* n0cnt = (int*)alloc(64);
    bf16* trc = (bf16*)alloc(384 * 2);
    bf16* Wuc = (bf16*)alloc(49152 * 2);
    bf16* buc = (bf16*)alloc(128 * 2);
    int* ec = (int*)alloc(2 * N_EDGES * 4);
    int* ccc = (int*)alloc(N_NODES * 4);

    // 1) detect dtypes + zero counters (no hipMemsetAsync anywhere)
    k_init<<<100, 256, 0, stream>>>((const unsigned short*)Wenc_r, e_r, flags,
                                    deg, ccount, n0cnt);
    // 2) all conversions + xin pad zero + edge/cluster counts + weight composition
    k_mega<<<KB_I, 256, 0, stream>>>(flags, cf_r, slf_r, z_r, tr_r, Wenc_r, benc_r,
                                     Wm_r, bm_r, Wu_r, bu_r, e_r, cc_r,
                                     xin, trc, Wuc, buc, ec, ccc, deg, ccount,
                                     Wc, bc, Wet, bcenc);
    // 3) block scans (deg) + cluster exclusive scan
    k_scan_a2<<<SCAN_B + 1, 1024, 0, stream>>>(deg, rowptr, bsum, ccount, coff, ccur);
    // 4) apply inter-block offsets (inlined scan_b)
    k_scan_c2<<<SCAN_B, 1024, 0, stream>>>(rowptr, cursor, bsum);
    // 5) encoder + CSR fills + deg-0 list
    k_front<<<K5_L0, 256, 0, stream>>>(xin, Wet, bcenc, xb0,
                                       ec, cursor, colx, ccc, ccur, cnodes,
                                       deg, n0list, n0cnt);

    bf16* xbufs[2] = {xb0, xb1};
    for (int layer = 0; layer < 3; layer++) {
        bf16* xbi = xbufs[layer & 1];
        bf16* xbo = xbufs[(layer + 1) & 1];
        int last = (layer == 2);
        k_aggpool<<<AGG_B + NBC, 256, 0, stream>>>(xbi, rowptr, colx, mb,
                                                   coff, cnodes, trc, pooled);
        k_fused2<<<GRID_F, 256, 0, stream>>>(xbi, mb, pooled, Wc, bc, ccc, deg,
                                             Wuc, buc, n0list, n0cnt,
                                             xbo, flags, d_out, last);
    }
}

// Round 2
// 428.275 us; speedup vs baseline: 1.4462x; 1.1154x over previous
//
#include <hip/hip_runtime.h>
#include <hip/hip_bf16.h>

#define N_NODES 100000
#define N_EDGES 600000
#define HD 128
#define NBC 384
#define SCAN_B 98   // ceil(N_NODES/1024)
#define MAXFIX 4096
#define TILES ((N_NODES + 63) / 64)  // 1563
#define GRID_F 512
#define AGG_B (N_NODES / 4)          // 25000
#define CAPB 16384                   // per-bucket edge capacity (mean 6122, 130 sigma headroom)
#define PB_BLK 147                   // ceil(600000/4096) pass-B blocks

typedef __attribute__((ext_vector_type(8))) short s8v;
typedef __attribute__((ext_vector_type(4))) short s4v;
typedef __attribute__((ext_vector_type(4))) float f4v;
typedef __hip_bfloat16 bf16;

static __device__ __forceinline__ float bf2f(bf16 v) { return __bfloat162float(v); }
static __device__ __forceinline__ bf16 f2bf(float v) { return __float2bfloat16(v); }
static __device__ __forceinline__ float sh2f(short s) { bf16 h = *(bf16*)&s; return bf2f(h); }
static __device__ __forceinline__ float ldraw(const void* p, int i, int fp32) {
    return fp32 ? ((const float*)p)[i] : bf2f(((const bf16*)p)[i]);
}

// async global->LDS, 16B per lane; lds dest = wave-uniform base + lane*16
static __device__ __forceinline__ void gl2lds16(const void* g, void* l) {
    __builtin_amdgcn_global_load_lds(
        (const __attribute__((address_space(1))) void*)g,
        (__attribute__((address_space(3))) void*)l, 16, 0, 0);
}

// ================= K1: dtype detect + zero deg/ccount/n0cnt/bcur ======
__global__ void k_init(const unsigned short* __restrict__ wraw, const int* __restrict__ eraw,
                       int* __restrict__ flags, int* __restrict__ deg,
                       int* __restrict__ ccount, int* __restrict__ n0cnt,
                       int* __restrict__ bcur) {
    int b = blockIdx.x, t = threadIdx.x;
    if (b == 0) {
        if (t < 64) {
            int bad = 0;
            for (int k = 0; k < 16; k++) {
                unsigned int u = ((unsigned int)wraw[t * 16 + k]) << 16;
                float f = fabsf(__uint_as_float(u));
                if (!(f <= 1e4f)) bad = 1;  // catches huge AND NaN
            }
            unsigned long long m = __ballot(bad);
            if (t == 0) {
                flags[0] = m ? 1 : 0;
                flags[1] = (eraw[1] == 0 && eraw[3] == 0 && eraw[5] == 0 && eraw[7] == 0) ? 1 : 0;
            }
        }
    } else if (b <= 98) {
        int i = (b - 1) * 256 + t;
        if (i < 25000) ((int4*)deg)[i] = make_int4(0, 0, 0, 0);   // 100000 ints
    } else {
        if (t < 96) ((int4*)ccount)[t] = make_int4(0, 0, 0, 0);   // 384 ints
        if (t == 96) *n0cnt = 0;
        if (t >= 128 && t < 128 + SCAN_B) bcur[t - 128] = 0;
    }
}

// ===== K2: mega conversion + counts + composed-weight prep (heavy blocks first) ==
#define KB_J 192              // Wc compose
#define KB_K (KB_J + 32)      // 224  Wet
#define KB_L (KB_K + 1)       // 225  bc + bcenc
#define KB_A (KB_L + 5860)    // 6085 cf
#define KB_B (KB_A + 391)     // 6476 slf
#define KB_C (KB_B + 12500)   // 18976 z
#define KB_D (KB_C + 782)     // 19758 xin pad zero
#define KB_E (KB_D + 2)       // 19760 tr
#define KB_F (KB_E + 192)     // 19952 Wu -> Wuc
#define KB_G (KB_F + 1)       // 19953 bu -> buc
#define KB_H (KB_G + 4688)    // 24641 e cvt + deg count
#define KB_I (KB_H + 391)     // 25032 cc cvt + cluster count
__global__ void k_mega(const int* __restrict__ flags,
                       const void* cf_r, const void* slf_r, const void* z_r,
                       const void* tr_r, const void* Wenc_r, const void* benc_r,
                       const void* Wm_r, const void* bm_r, const void* Wu_r,
                       const void* bu_r, const int* __restrict__ e_r,
                       const int* __restrict__ cc_r,
                       bf16* __restrict__ xin, bf16* __restrict__ trc,
                       bf16* __restrict__ Wuc, bf16* __restrict__ buc,
                       int* __restrict__ ec, int* __restrict__ ccc,
                       int* __restrict__ deg, int* __restrict__ ccount,
                       bf16* __restrict__ Wc, float* __restrict__ bc,
                       bf16* __restrict__ Wet, float* __restrict__ bcenc) {
    int b = blockIdx.x, t = threadIdx.x;
    int fp32 = flags[0];
    if (b < KB_J) {           // compose Wc from RAW Wm/Wu (flag-dispatched loads)
        int i = b * 256 + t;  // < 49152
        int w = i / 384, kk = i - w * 384;
        float acc = 0.f;
        if (kk < 128) {
            acc = ldraw(Wu_r, kk * 128 + w, fp32);
            for (int j = 0; j < 128; j++)
                acc += ldraw(Wm_r, kk * 128 + j, fp32) * ldraw(Wu_r, (128 + j) * 128 + w, fp32);
        } else if (kk < 256) {
            int kp = kk - 128;
            for (int j = 0; j < 128; j++)
                acc += ldraw(Wm_r, (128 + kp) * 128 + j, fp32) * ldraw(Wu_r, (128 + j) * 128 + w, fp32);
        } else {
            acc = ldraw(Wu_r, kk * 128 + w, fp32);
        }
        Wc[w * 384 + kk] = f2bf(acc);
    } else if (b < KB_K) {    // Wet: transposed, zero-padded encoder weight
        int i = (b - KB_J) * 256 + t;  // < 8192
        int w = i >> 6, kk = i & 63;
        float v = (kk < 48) ? ldraw(Wenc_r, kk * 128 + w, fp32) : 0.f;
        Wet[i] = f2bf(v);
    } else if (b < KB_L) {    // bc compose + bcenc
        if (t < 128) {
            float acc = ldraw(bu_r, t, fp32);
            for (int j = 0; j < 128; j++)
                acc += ldraw(bm_r, j, fp32) * ldraw(Wu_r, (128 + j) * 128 + t, fp32);
            bc[t] = acc;
        } else if (t < 256) {
            bcenc[t - 128] = ldraw(benc_r, t - 128, fp32);
        }
    } else if (b < KB_A) {    // cf -> xin cols 0..14
        int i = (b - KB_L) * 256 + t;
        if (i < 1500000) {
            int node = i / 15;
            xin[(size_t)node * 64 + (i - node * 15)] = f2bf(ldraw(cf_r, i, fp32));
        }
    } else if (b < KB_B) {    // slf -> col 15
        int i = (b - KB_A) * 256 + t;
        if (i < 100000) xin[(size_t)i * 64 + 15] = f2bf(ldraw(slf_r, i, fp32));
    } else if (b < KB_C) {    // z -> cols 16..47
        int i = (b - KB_B) * 256 + t;
        if (i < 3200000) xin[(size_t)(i >> 5) * 64 + 16 + (i & 31)] = f2bf(ldraw(z_r, i, fp32));
    } else if (b < KB_D) {    // pad cols 48..63 zero
        int p = (b - KB_C) * 2048 + t * 8;
        if (p < 1600000) {
            int row = p >> 4, off = p & 15;  // off in {0,8}
            s8v zz = {0, 0, 0, 0, 0, 0, 0, 0};
            *(s8v*)((short*)xin + (size_t)row * 64 + 48 + off) = zz;
        }
    } else if (b < KB_E) {    // tr -> trc
        int i = (b - KB_D) * 256 + t;
        if (i < 384) trc[i] = f2bf(ldraw(tr_r, i, fp32));
    } else if (b < KB_F) {    // Wu -> Wuc (for deg-0 fixup)
        int i = (b - KB_E) * 256 + t;  // < 49152 exact
        Wuc[i] = f2bf(ldraw(Wu_r, i, fp32));
    } else if (b < KB_G) {    // bu -> buc
        if (t < 128) buc[t] = f2bf(ldraw(bu_r, t, fp32));
    } else if (b < KB_H) {    // e cvt + degree count fused
        int i64f = flags[1];
        int i = (b - KB_G) * 256 + t;
        if (i < 2 * N_EDGES) {
            int v = i64f ? e_r[2 * i] : e_r[i];
            ec[i] = v;
            if (i >= N_EDGES) atomicAdd(&deg[v], 1);
        }
    } else {                  // cc cvt + cluster count fused
        int i64f = flags[1];
        int i = (b - KB_H) * 256 + t;
        if (i < N_NODES) {
            int v = i64f ? cc_r[2 * i] : cc_r[i];
            ccc[i] = v;
            atomicAdd(&ccount[v], 1);
        }
    }
}

// === K3: deg block-scan (0..97) + cluster scan (98) + edge bucket-bin (99..245) ==
__global__ void k_scan_a2(const int* __restrict__ deg, int* __restrict__ rowptr,
                          int* __restrict__ bsum, const int* __restrict__ ccount,
                          int* __restrict__ coff, int* __restrict__ ccur,
                          const int* __restrict__ ec, int* __restrict__ bcur,
                          int* __restrict__ ebuf) {
    __shared__ int sd[1024];
    __shared__ int hist[SCAN_B], hbase[SCAN_B], lcur[SCAN_B];
    int t = threadIdx.x;
    if (blockIdx.x < SCAN_B) {
        int i = blockIdx.x * 1024 + t;
        int v = (i < N_NODES) ? deg[i] : 0;
        sd[t] = v;
        __syncthreads();
#pragma unroll
        for (int off = 1; off < 1024; off <<= 1) {
            int u = (t >= off) ? sd[t - off] : 0;
            __syncthreads();
            sd[t] += u;
            __syncthreads();
        }
        if (i < N_NODES) rowptr[i] = sd[t] - v;
        if (t == 1023) bsum[blockIdx.x] = sd[t];
    } else if (blockIdx.x == SCAN_B) {
        int v = (t < NBC) ? ccount[t] : 0;
        sd[t] = v;
        __syncthreads();
#pragma unroll
        for (int off = 1; off < 1024; off <<= 1) {
            int u = (t >= off) ? sd[t - off] : 0;
            __syncthreads();
            sd[t] += u;
            __syncthreads();
        }
        if (t < NBC) {
            int ex = sd[t] - v;
            coff[t] = ex;
            ccur[t] = ex;
            if (t == NBC - 1) coff[NBC] = sd[t];
        }
    } else {
        // ---- pass B: bin edges (packed (src<<10)|(dst&1023)) into 98 bucket regions
        int bb = blockIdx.x - (SCAN_B + 1);
        int e0 = bb * 4096;
        if (t < SCAN_B) { hist[t] = 0; lcur[t] = 0; }
        __syncthreads();
        int dv[4], sv[4], bk[4];
#pragma unroll
        for (int k = 0; k < 4; k++) {
            int i = e0 + k * 1024 + t;
            if (i < N_EDGES) {
                dv[k] = ec[N_EDGES + i];
                sv[k] = ec[i];
                bk[k] = dv[k] >> 10;
                atomicAdd(&hist[bk[k]], 1);
            } else bk[k] = -1;
        }
        __syncthreads();
        if (t < SCAN_B && hist[t] > 0) hbase[t] = atomicAdd(&bcur[t], hist[t]);
        __syncthreads();
#pragma unroll
        for (int k = 0; k < 4; k++) {
            if (bk[k] >= 0) {
                int rel = hbase[bk[k]] + atomicAdd(&lcur[bk[k]], 1);
                if (rel < CAPB) ebuf[bk[k] * CAPB + rel] = (sv[k] << 10) | (dv[k] & 1023);
            }
        }
    }
}

// ====== K4: apply block offsets to rowptr (each block sums bsum prefix itself) ===
__global__ void k_scan_c2(int* __restrict__ rowptr, const int* __restrict__ bsum) {
    __shared__ int sb[128];
    __shared__ int offs;
    int b = blockIdx.x, t = threadIdx.x;
    if (t < 128) sb[t] = (t < b) ? bsum[t] : 0;   // b <= 97 < 128
    __syncthreads();
    if (t == 0) {
        int s = 0;
        for (int k = 0; k < 128; k++) s += sb[k];
        offs = s;
    }
    __syncthreads();
    int i = b * 1024 + t;
    if (i < N_NODES) rowptr[i] = rowptr[i] + offs;
    if (b == 0 && t == 0) rowptr[N_NODES] = N_EDGES;
}

// == K5: encoder MFMA + CSR fill (pass C, LDS cursors) + cluster fill + deg0 list ==
#define K5_EN 1563
#define K5_PC (K5_EN + SCAN_B)   // 1661
#define K5_CF (K5_PC + SCAN_B)   // 1759
#define K5_L0 (K5_CF + 391)      // 2150
__global__ void k_front(const bf16* __restrict__ xin, const bf16* __restrict__ Wet,
                        const float* __restrict__ bcenc, bf16* __restrict__ xb,
                        const int* __restrict__ rowptr, const int* __restrict__ ebuf,
                        int* __restrict__ colx, const int* __restrict__ ccc,
                        int* __restrict__ ccur, int* __restrict__ cnodes,
                        const int* __restrict__ deg, int* __restrict__ n0list,
                        int* __restrict__ n0cnt) {
    __shared__ int cur[1024];
    __shared__ int h[NBC], cb[NBC];
    int b = blockIdx.x;
    if (b >= K5_EN) {
        if (b < K5_PC) {
            // ---- pass C: scatter bucket's edges into CSR window via LDS cursors
            int bb = b - K5_EN;
            int base = bb << 10;
            int nlim = min(1024, N_NODES - base);
            for (int i = threadIdx.x; i < nlim; i += 256) cur[i] = rowptr[base + i];
            __syncthreads();
            int cnt = rowptr[base + nlim] - rowptr[base];
            const int* eb = ebuf + bb * CAPB;
            for (int e = threadIdx.x; e < cnt; e += 256) {
                int v = eb[e];
                int p = atomicAdd(&cur[v & 1023], 1);
                colx[p] = v >> 10;
            }
        } else if (b < K5_CF) {
            // ---- cluster-node fill via LDS histogram + chunk reservation
            int bb = b - K5_PC;
            int base = bb << 10;
            int nlim = min(1024, N_NODES - base);
            for (int j = threadIdx.x; j < NBC; j += 256) h[j] = 0;
            __syncthreads();
            int cls[4];
#pragma unroll
            for (int k = 0; k < 4; k++) {
                int li = k * 256 + threadIdx.x;
                cls[k] = (li < nlim) ? ccc[base + li] : -1;
                if (cls[k] >= 0) atomicAdd(&h[cls[k]], 1);
            }
            __syncthreads();
            for (int j = threadIdx.x; j < NBC; j += 256) {
                cb[j] = h[j] ? atomicAdd(&ccur[j], h[j]) : 0;
                h[j] = 0;
            }
            __syncthreads();
#pragma unroll
            for (int k = 0; k < 4; k++) {
                if (cls[k] >= 0) {
                    int p = cb[cls[k]] + atomicAdd(&h[cls[k]], 1);
                    cnodes[p] = base + k * 256 + threadIdx.x;
                }
            }
        } else {
            // ---- deg-0 list
            int i = (b - K5_CF) * 256 + threadIdx.x;
            if (i < N_NODES && deg[i] == 0) {
                int p = atomicAdd(n0cnt, 1);
                if (p < MAXFIX) n0list[p] = i;
            }
        }
        return;
    }
    // ---- MFMA encoder: xb = bf16( xin[N,64] @ Wet^T + benc ) ----
    int tid = threadIdx.x;
    int r0 = b * 64;
    int wave = tid >> 6, lane = tid & 63, quad = lane >> 4, nidx = lane & 15;
    int colbase = wave * 32;

    int arow[4];
#pragma unroll
    for (int rt = 0; rt < 4; rt++) {
        int gr = r0 + rt * 16 + nidx;
        arow[rt] = (gr < N_NODES) ? gr : (N_NODES - 1);
    }
    f4v acc[4][2];
#pragma unroll
    for (int rt = 0; rt < 4; rt++)
#pragma unroll
        for (int ct = 0; ct < 2; ct++) acc[rt][ct] = (f4v){0.f, 0.f, 0.f, 0.f};

#pragma unroll
    for (int s = 0; s < 2; s++) {
        int k0 = s * 32;
        s8v bfrag[4];
#pragma unroll
        for (int rt = 0; rt < 4; rt++)
            bfrag[rt] = *(const s8v*)((const short*)xin + (size_t)arow[rt] * 64 + k0 + quad * 8);
#pragma unroll
        for (int ct = 0; ct < 2; ct++) {
            s8v wfr = *(const s8v*)((const short*)Wet + (colbase + ct * 16 + nidx) * 64 + k0 + quad * 8);
#pragma unroll
            for (int rt = 0; rt < 4; rt++)
                acc[rt][ct] = __builtin_amdgcn_mfma_f32_16x16x32_bf16(wfr, bfrag[rt], acc[rt][ct], 0, 0, 0);
        }
    }
#pragma unroll
    for (int rt = 0; rt < 4; rt++) {
        int gr = r0 + rt * 16 + nidx;
        if (gr < N_NODES) {
#pragma unroll
            for (int ct = 0; ct < 2; ct++) {
                int wc0 = colbase + ct * 16 + quad * 4;
                f4v bv = *(const f4v*)(bcenc + wc0);
                size_t idx = (size_t)gr * HD + wc0;
                s4v ob;
#pragma unroll
                for (int r = 0; r < 4; r++) {
                    float nv = acc[rt][ct][r] + bv[r];
                    bf16 h2 = f2bf(nv);
                    ob[r] = *(short*)&h2;
                }
                *(s4v*)((short*)xb + idx) = ob;
            }
        }
    }
}

// ====== K6 (per layer): cluster pooling (blocks 0..383) + edge aggregation =======
__global__ void k_aggpool(const bf16* __restrict__ xb, const int* __restrict__ rowptr,
                          const int* __restrict__ colx, bf16* __restrict__ mb,
                          const int* __restrict__ coff, const int* __restrict__ cnodes,
                          const bf16* __restrict__ trc, bf16* __restrict__ pooled) {
    __shared__ float red[8][128];
    int tid = threadIdx.x;
    if (blockIdx.x < NBC) {
        int cl = blockIdx.x;
        int lo = coff[cl], hi = coff[cl + 1];
        int cnt = hi - lo;
        int slot = tid >> 5, cg = tid & 31;
        float a0 = 0.f, a1 = 0.f, a2 = 0.f, a3 = 0.f;
        for (int i = lo + slot; i < hi; i += 8) {
            int nd = cnodes[i];
            s4v v = *(const s4v*)((const short*)xb + (size_t)nd * HD + cg * 4);
            a0 += sh2f(v[0]); a1 += sh2f(v[1]); a2 += sh2f(v[2]); a3 += sh2f(v[3]);
        }
        red[slot][cg * 4 + 0] = a0;
        red[slot][cg * 4 + 1] = a1;
        red[slot][cg * 4 + 2] = a2;
        red[slot][cg * 4 + 3] = a3;
        __syncthreads();
        if (tid < 128) {
            float s = 0.f;
#pragma unroll
            for (int k = 0; k < 8; k++) s += red[k][tid];
            float v = s / (float)(cnt > 1 ? cnt : 1) * bf2f(trc[cl]);
            pooled[cl * HD + tid] = f2bf(v);
        }
        return;
    }
    // ---- aggregation: mean of x[src] over incoming edges ----
    int wave = tid >> 6, lane = tid & 63;
    int node = (blockIdx.x - NBC) * 4 + wave;
    if (node >= N_NODES) return;
    int half = lane >> 5;
    int l = lane & 31;
    int lo = rowptr[node], hi = rowptr[node + 1];
    float a0 = 0.f, a1 = 0.f, a2 = 0.f, a3 = 0.f;
    int j = lo + half;
    while (j + 2 < hi) {
        int s0 = colx[j], s1 = colx[j + 2];
        s4v v0 = *(const s4v*)((const short*)xb + (size_t)s0 * HD + l * 4);
        s4v v1 = *(const s4v*)((const short*)xb + (size_t)s1 * HD + l * 4);
        a0 += sh2f(v0[0]) + sh2f(v1[0]);
        a1 += sh2f(v0[1]) + sh2f(v1[1]);
        a2 += sh2f(v0[2]) + sh2f(v1[2]);
        a3 += sh2f(v0[3]) + sh2f(v1[3]);
        j += 4;
    }
    if (j < hi) {
        int s0 = colx[j];
        s4v v0 = *(const s4v*)((const short*)xb + (size_t)s0 * HD + l * 4);
        a0 += sh2f(v0[0]);
        a1 += sh2f(v0[1]);
        a2 += sh2f(v0[2]);
        a3 += sh2f(v0[3]);
    }
    a0 += __shfl_down(a0, 32);
    a1 += __shfl_down(a1, 32);
    a2 += __shfl_down(a2, 32);
    a3 += __shfl_down(a3, 32);
    if (half == 0) {
        int d = hi - lo;
        float inv = 1.0f / (float)(d > 1 ? d : 1);
        s4v o;
        bf16 h0 = f2bf(a0 * inv); o[0] = *(short*)&h0;
        bf16 h1 = f2bf(a1 * inv); o[1] = *(short*)&h1;
        bf16 h2 = f2bf(a2 * inv); o[2] = *(short*)&h2;
        bf16 h3 = f2bf(a3 * inv); o[3] = *(short*)&h3;
        *(s4v*)((short*)mb + (size_t)node * HD + l * 4) = o;
    }
}

// ====== K7 (per layer): fused update (persistent, LDS-staged) + deg-0 fixup ======
__global__ __launch_bounds__(256, 2) void k_fused2(
    const bf16* __restrict__ xb, const bf16* __restrict__ mb, const bf16* __restrict__ pooled,
    const bf16* __restrict__ Wc, const float* __restrict__ bc,
    const int* __restrict__ cc, const int* __restrict__ deg,
    const bf16* __restrict__ Wuc, const bf16* __restrict__ buc,
    const int* __restrict__ n0list, const int* __restrict__ n0cnt,
    bf16* __restrict__ xbo, const int* __restrict__ flags,
    void* __restrict__ out, int last) {
    __shared__ short Lx[64 * 128];
    __shared__ short Lm[64 * 128];
    __shared__ short Lp[64 * 128];
    __shared__ float fxv[128];
    __shared__ float fpv[128];
    int tid = threadIdx.x;
    int wave = tid >> 6, lane = tid & 63, quad = lane >> 4, nidx = lane & 15;
    int colbase = wave * 32;
    int fp32out = flags[0];

    s8v wfr[12][2];
#pragma unroll
    for (int ct = 0; ct < 2; ct++) {
        int wcol = colbase + ((nidx >> 2) << 3) + ct * 4 + (nidx & 3);
        const short* wrow = (const short*)Wc + (size_t)wcol * 384 + quad * 8;
#pragma unroll
        for (int s = 0; s < 12; s++) wfr[s][ct] = *(const s8v*)(wrow + s * 32);
    }
    int cb2 = colbase + quad * 8;
    f4v bv0 = *(const f4v*)(bc + cb2);
    f4v bv1 = *(const f4v*)(bc + cb2 + 4);

    int srow = lane >> 4;
    int sc = lane & 15;

    for (int t = blockIdx.x; t < TILES; t += GRID_F) {
        int r0 = t * 64;
#pragma unroll
        for (int ii = 0; ii < 4; ii++) {
            int i = wave * 4 + ii;
            int lr = i * 4 + srow;
            int gr = r0 + lr;
            int grc = (gr < N_NODES) ? gr : (N_NODES - 1);
            int gc = sc ^ (lr & 15);
            gl2lds16((const short*)xb + (size_t)grc * HD + gc * 8, (char*)Lx + i * 1024);
            gl2lds16((const short*)mb + (size_t)grc * HD + gc * 8, (char*)Lm + i * 1024);
            int ci = cc[grc];
            gl2lds16((const short*)pooled + (size_t)ci * HD + gc * 8, (char*)Lp + i * 1024);
        }
        __syncthreads();

        f4v acc[4][2];
#pragma unroll
        for (int rt = 0; rt < 4; rt++)
#pragma unroll
            for (int ct = 0; ct < 2; ct++) acc[rt][ct] = (f4v){0.f, 0.f, 0.f, 0.f};

#pragma unroll
        for (int s = 0; s < 12; s++) {
            const short* Ls = (s < 4) ? Lx : ((s < 8) ? Lm : Lp);
            int c = (s & 3) * 4 + quad;
            s8v bfrag[4];
#pragma unroll
            for (int rt = 0; rt < 4; rt++) {
                int row = rt * 16 + nidx;
                int slot = c ^ nidx;
                bfrag[rt] = *(const s8v*)(Ls + row * 128 + slot * 8);
            }
#pragma unroll
            for (int ct = 0; ct < 2; ct++)
#pragma unroll
                for (int rt = 0; rt < 4; rt++)
                    acc[rt][ct] = __builtin_amdgcn_mfma_f32_16x16x32_bf16(wfr[s][ct], bfrag[rt], acc[rt][ct], 0, 0, 0);
        }

#pragma unroll
        for (int rt = 0; rt < 4; rt++) {
            int gr = r0 + rt * 16 + nidx;
            if (gr < N_NODES && deg[gr] > 0) {
                int row = rt * 16 + nidx;
                int slot = ((colbase >> 3) + quad) ^ nidx;
                s8v xo = *(const s8v*)(Lx + row * 128 + slot * 8);
                size_t idx = (size_t)gr * HD + cb2;
                float nv[8];
#pragma unroll
                for (int r = 0; r < 4; r++) {
                    float v0 = acc[rt][0][r] + bv0[r];
                    v0 = (v0 > 0.f) ? v0 : 0.01f * v0;
                    nv[r] = sh2f(xo[r]) + v0;
                    float v1 = acc[rt][1][r] + bv1[r];
                    v1 = (v1 > 0.f) ? v1 : 0.01f * v1;
                    nv[4 + r] = sh2f(xo[4 + r]) + v1;
                }
                if (last) {
                    if (fp32out) {
                        f4v o0 = {nv[0], nv[1], nv[2], nv[3]};
                        f4v o1 = {nv[4], nv[5], nv[6], nv[7]};
                        *(f4v*)((float*)out + idx) = o0;
                        *(f4v*)((float*)out + idx + 4) = o1;
                    } else {
                        s8v ob;
#pragma unroll
                        for (int r = 0; r < 8; r++) { bf16 h = f2bf(nv[r]); ob[r] = *(short*)&h; }
                        *(s8v*)((short*)out + idx) = ob;
                    }
                } else {
                    s8v ob;
#pragma unroll
                    for (int r = 0; r < 8; r++) { bf16 h = f2bf(nv[r]); ob[r] = *(short*)&h; }
                    *(s8v*)((short*)xbo + idx) = ob;
                }
            }
        }
        __syncthreads();
    }

    // ---- deg-0 fixup tail (disjoint rows; fused2 skipped deg==0) ----
    int cnt0 = *n0cnt;
    if (cnt0 > MAXFIX) cnt0 = MAXFIX;
    for (int j = blockIdx.x; j < cnt0; j += gridDim.x) {
        int v = n0list[j];
        if (tid < 128) {
            fxv[tid] = bf2f(xb[(size_t)v * HD + tid]);
            fpv[tid] = bf2f(pooled[cc[v] * HD + tid]);
        }
        __syncthreads();
        if (tid < 128) {
            float acc = bf2f(buc[tid]);
            for (int k = 0; k < 128; k++)
                acc += fxv[k] * bf2f(Wuc[k * 128 + tid]) + fpv[k] * bf2f(Wuc[(256 + k) * 128 + tid]);
            float u = acc > 0.f ? acc : 0.01f * acc;
            size_t idx = (size_t)v * HD + tid;
            float nv = fxv[tid] + u;
            if (last) {
                if (fp32out) ((float*)out)[idx] = nv;
                else ((bf16*)out)[idx] = f2bf(nv);
            } else {
                xbo[idx] = f2bf(nv);
            }
        }
        __syncthreads();
    }
}

extern "C" void kernel_launch(void* const* d_in, const int* in_sizes, int n_in,
                              void* d_out, int out_size, void* d_ws, size_t ws_size,
                              hipStream_t stream) {
    const void* cf_r = d_in[0];
    const void* slf_r = d_in[1];
    const void* z_r = d_in[2];
    const void* tr_r = d_in[3];
    const void* Wenc_r = d_in[4];
    const void* benc_r = d_in[5];
    const void* Wm_r = d_in[6];
    const void* bm_r = d_in[7];
    const void* Wu_r = d_in[8];
    const void* bu_r = d_in[9];
    const int* e_r = (const int*)d_in[10];
    const int* cc_r = (const int*)d_in[11];

    char* w = (char*)d_ws;
    auto alloc = [&](size_t bytes) -> char* {
        char* p = w;
        w += (bytes + 63) & ~(size_t)63;
        return p;
    };
    bf16* xb0 = (bf16*)alloc((size_t)N_NODES * HD * 2);
    bf16* xb1 = (bf16*)alloc((size_t)N_NODES * HD * 2);
    bf16* mb = (bf16*)alloc((size_t)N_NODES * HD * 2);
    bf16* xin = (bf16*)alloc((size_t)N_NODES * 64 * 2);
    bf16* Wc = (bf16*)alloc(128 * 384 * 2);
    float* bc = (float*)alloc(128 * 4);
    bf16* Wet = (bf16*)alloc(128 * 64 * 2);
    float* bcenc = (float*)alloc(128 * 4);
    bf16* pooled = (bf16*)alloc(NBC * HD * 2);
    int* deg = (int*)alloc(N_NODES * 4);
    int* rowptr = (int*)alloc((N_NODES + 1) * 4);
    int* colx = (int*)alloc(N_EDGES * 4);
    int* ccount = (int*)alloc(NBC * 4);
    int* coff = (int*)alloc((NBC + 1) * 4);
    int* ccur = (int*)alloc(NBC * 4);
    int* cnodes = (int*)alloc(N_NODES * 4);
    int* flags = (int*)alloc(64);
    int* bsum = (int*)alloc(SCAN_B * 4);
    int* n0list = (int*)alloc(MAXFIX * 4);
    int* n0cnt = (int*)alloc(64);
    bf16* trc = (bf16*)alloc(384 * 2);
    bf16* Wuc = (bf16*)alloc(49152 * 2);
    bf16* buc = (bf16*)alloc(128 * 2);
    int* ec = (int*)alloc(2 * N_EDGES * 4);
    int* ccc = (int*)alloc(N_NODES * 4);
    int* bcur = (int*)alloc(SCAN_B * 4);
    int* ebuf = (int*)alloc((size_t)SCAN_B * CAPB * 4);   // 6.4 MB

    // 1) detect dtypes + zero counters
    k_init<<<100, 256, 0, stream>>>((const unsigned short*)Wenc_r, e_r, flags,
                                    deg, ccount, n0cnt, bcur);
    // 2) all conversions + xin pad zero + edge/cluster counts + weight composition
    k_mega<<<KB_I, 256, 0, stream>>>(flags, cf_r, slf_r, z_r, tr_r, Wenc_r, benc_r,
                                     Wm_r, bm_r, Wu_r, bu_r, e_r, cc_r,
                                     xin, trc, Wuc, buc, ec, ccc, deg, ccount,
                                     Wc, bc, Wet, bcenc);
    // 3) deg block-scans + cluster scan + edge bucket-binning (pass B)
    k_scan_a2<<<SCAN_B + 1 + PB_BLK, 1024, 0, stream>>>(deg, rowptr, bsum, ccount,
                                                        coff, ccur, ec, bcur, ebuf);
    // 4) finalize rowptr
    k_scan_c2<<<SCAN_B, 1024, 0, stream>>>(rowptr, bsum);
    // 5) encoder + CSR fill (pass C) + cluster fill + deg-0 list
    k_front<<<K5_L0, 256, 0, stream>>>(xin, Wet, bcenc, xb0,
                                       rowptr, ebuf, colx, ccc, ccur, cnodes,
                                       deg, n0list, n0cnt);

    bf16* xbufs[2] = {xb0, xb1};
    for (int layer = 0; layer < 3; layer++) {
        bf16* xbi = xbufs[layer & 1];
        bf16* xbo = xbufs[(layer + 1) & 1];
        int last = (layer == 2);
        k_aggpool<<<AGG_B + NBC, 256, 0, stream>>>(xbi, rowptr, colx, mb,
                                                   coff, cnodes, trc, pooled);
        k_fused2<<<GRID_F, 256, 0, stream>>>(xbi, mb, pooled, Wc, bc, ccc, deg,
                                             Wuc, buc, n0list, n0cnt,
                                             xbo, flags, d_out, last);
    }
}

// Round 3
// 420.133 us; speedup vs baseline: 1.4743x; 1.0194x over previous
//
#include <hip/hip_runtime.h>
#include <hip/hip_bf16.h>

#define N_NODES 100000
#define N_EDGES 600000
#define HD 128
#define NBC 384
#define SCAN_B 98   // ceil(N_NODES/1024)
#define MAXFIX 4096
#define TILES ((N_NODES + 63) / 64)  // 1563
#define GRID_F 512
#define AGG_B (N_NODES / 4)          // 25000
#define CAPB 16384                   // per-bucket edge capacity (mean 6122)

typedef __attribute__((ext_vector_type(8))) short s8v;
typedef __attribute__((ext_vector_type(4))) short s4v;
typedef __attribute__((ext_vector_type(4))) float f4v;
typedef __hip_bfloat16 bf16;

static __device__ __forceinline__ float bf2f(bf16 v) { return __bfloat162float(v); }
static __device__ __forceinline__ bf16 f2bf(float v) { return __float2bfloat16(v); }
static __device__ __forceinline__ float sh2f(short s) { bf16 h = *(bf16*)&s; return bf2f(h); }
static __device__ __forceinline__ float ldraw(const void* p, int i, int fp32) {
    return fp32 ? ((const float*)p)[i] : bf2f(((const bf16*)p)[i]);
}

// async global->LDS, 16B per lane; lds dest = wave-uniform base + lane*16
static __device__ __forceinline__ void gl2lds16(const void* g, void* l) {
    __builtin_amdgcn_global_load_lds(
        (const __attribute__((address_space(1))) void*)g,
        (__attribute__((address_space(3))) void*)l, 16, 0, 0);
}

// ================= K1: dtype detect + zero deg/ccount/n0cnt/bcur ======
__global__ void k_init(const unsigned short* __restrict__ wraw, const int* __restrict__ eraw,
                       int* __restrict__ flags, int* __restrict__ deg,
                       int* __restrict__ ccount, int* __restrict__ n0cnt,
                       int* __restrict__ bcur) {
    int b = blockIdx.x, t = threadIdx.x;
    if (b == 0) {
        if (t < 64) {
            int bad = 0;
            for (int k = 0; k < 16; k++) {
                unsigned int u = ((unsigned int)wraw[t * 16 + k]) << 16;
                float f = fabsf(__uint_as_float(u));
                if (!(f <= 1e4f)) bad = 1;  // catches huge AND NaN
            }
            unsigned long long m = __ballot(bad);
            if (t == 0) {
                flags[0] = m ? 1 : 0;
                flags[1] = (eraw[1] == 0 && eraw[3] == 0 && eraw[5] == 0 && eraw[7] == 0) ? 1 : 0;
            }
        }
    } else if (b <= 98) {
        int i = (b - 1) * 256 + t;
        if (i < 25000) ((int4*)deg)[i] = make_int4(0, 0, 0, 0);   // 100000 ints
    } else {
        if (t < 96) ((int4*)ccount)[t] = make_int4(0, 0, 0, 0);   // 384 ints
        if (t == 96) *n0cnt = 0;
        if (t >= 128 && t < 128 + SCAN_B) bcur[t - 128] = 0;
    }
}

// ===== K2: mega kernel — compose + edge-bin + xin rows + cc + weight copies =====
#define KB_COMP 192                 // Wc compose (wave-friendly mapping)
#define KB_EDGE (KB_COMP + 586)    // 778  edge cvt + deg count + bucket bin
#define KB_XIN  (KB_EDGE + 391)    // 1169 xin full-row build
#define KB_CC   (KB_XIN + 391)     // 1560 cc cvt + cluster count
#define KB_WUC  (KB_CC + 192)      // 1752 Wu -> Wuc
#define KB_WET  (KB_WUC + 32)      // 1784 Wet
#define KB_BC   (KB_WET + 1)       // 1785 bc + bcenc + buc
#define KB_TR   (KB_BC + 2)        // 1787 trc
__global__ void k_mega(const int* __restrict__ flags,
                       const void* cf_r, const void* slf_r, const void* z_r,
                       const void* tr_r, const void* Wenc_r, const void* benc_r,
                       const void* Wm_r, const void* bm_r, const void* Wu_r,
                       const void* bu_r, const int* __restrict__ e_r,
                       const int* __restrict__ cc_r,
                       bf16* __restrict__ xin, bf16* __restrict__ trc,
                       bf16* __restrict__ Wuc, bf16* __restrict__ buc,
                       int* __restrict__ ccc,
                       int* __restrict__ deg, int* __restrict__ ccount,
                       bf16* __restrict__ Wc, float* __restrict__ bc,
                       bf16* __restrict__ Wet, float* __restrict__ bcenc,
                       int* __restrict__ bcur, int* __restrict__ ebuf) {
    __shared__ float scf[3840];                       // cf staging (15KB)
    __shared__ int hist[SCAN_B], hbase[SCAN_B], lcur[SCAN_B];
    int b = blockIdx.x, t = threadIdx.x;
    int fp32 = flags[0];
    if (b < KB_COMP) {
        // ---- Wc compose: w lane-consecutive, kk wave-uniform ----
        int i = b * 256 + t;          // < 49152
        int w = i & 127, kk = i >> 7; // kk in [0,384)
        float acc = 0.f;
        if (kk < 128) {
            acc = ldraw(Wu_r, kk * 128 + w, fp32);
#pragma unroll 8
            for (int j = 0; j < 128; j++)
                acc += ldraw(Wm_r, kk * 128 + j, fp32) * ldraw(Wu_r, (128 + j) * 128 + w, fp32);
        } else if (kk < 256) {
            int kp = kk - 128;
#pragma unroll 8
            for (int j = 0; j < 128; j++)
                acc += ldraw(Wm_r, (128 + kp) * 128 + j, fp32) * ldraw(Wu_r, (128 + j) * 128 + w, fp32);
        } else {
            acc = ldraw(Wu_r, kk * 128 + w, fp32);
        }
        Wc[w * 384 + kk] = f2bf(acc);
    } else if (b < KB_EDGE) {
        // ---- edge cvt + degree count + bucket binning (packed (src<<10)|(dst&1023))
        int i64f = flags[1];
        int bb = b - KB_COMP;
        int e0 = bb * 1024;
        if (t < SCAN_B) { hist[t] = 0; lcur[t] = 0; }
        __syncthreads();
        int sv[4], dv[4], bk[4];
#pragma unroll
        for (int k = 0; k < 4; k++) {
            int i = e0 + k * 256 + t;
            if (i < N_EDGES) {
                sv[k] = i64f ? e_r[2 * i] : e_r[i];
                dv[k] = i64f ? e_r[2 * (N_EDGES + i)] : e_r[N_EDGES + i];
                bk[k] = dv[k] >> 10;
                atomicAdd(&hist[bk[k]], 1);
                atomicAdd(&deg[dv[k]], 1);
            } else bk[k] = -1;
        }
        __syncthreads();
        if (t < SCAN_B && hist[t] > 0) hbase[t] = atomicAdd(&bcur[t], hist[t]);
        __syncthreads();
#pragma unroll
        for (int k = 0; k < 4; k++) {
            if (bk[k] >= 0) {
                int rel = hbase[bk[k]] + atomicAdd(&lcur[bk[k]], 1);
                if (rel < CAPB) ebuf[bk[k] * CAPB + rel] = (sv[k] << 10) | (dv[k] & 1023);
            }
        }
    } else if (b < KB_XIN) {
        // ---- xin: one full 64-col row per thread; full-line 16B stores ----
        int base = (b - KB_EDGE) * 256;   // node base
        int gbase = base * 15;
        int cnt = min(3840, 1500000 - gbase);
        for (int k = t; k < cnt; k += 256) scf[k] = ldraw(cf_r, gbase + k, fp32);
        __syncthreads();
        int node = base + t;
        if (node < N_NODES) {
            float vals[64];
#pragma unroll
            for (int k = 0; k < 64; k++) vals[k] = 0.f;
#pragma unroll
            for (int k = 0; k < 15; k++) vals[k] = scf[t * 15 + k];
            vals[15] = ldraw(slf_r, node, fp32);
            if (fp32) {
                const f4v* zp = (const f4v*)((const float*)z_r + (size_t)node * 32);
#pragma unroll
                for (int k = 0; k < 8; k++) {
                    f4v v = zp[k];
#pragma unroll
                    for (int r = 0; r < 4; r++) vals[16 + k * 4 + r] = v[r];
                }
            } else {
                const s8v* zp = (const s8v*)((const short*)z_r + (size_t)node * 32);
#pragma unroll
                for (int k = 0; k < 4; k++) {
                    s8v v = zp[k];
#pragma unroll
                    for (int r = 0; r < 8; r++) vals[16 + k * 8 + r] = sh2f(v[r]);
                }
            }
            short* xr = (short*)xin + (size_t)node * 64;
#pragma unroll
            for (int k = 0; k < 8; k++) {
                s8v ov;
#pragma unroll
                for (int r = 0; r < 8; r++) { bf16 h = f2bf(vals[k * 8 + r]); ov[r] = *(short*)&h; }
                *(s8v*)(xr + k * 8) = ov;
            }
        }
    } else if (b < KB_CC) {
        // ---- cc cvt + cluster count ----
        int i64f = flags[1];
        int i = (b - KB_XIN) * 256 + t;
        if (i < N_NODES) {
            int v = i64f ? cc_r[2 * i] : cc_r[i];
            ccc[i] = v;
            atomicAdd(&ccount[v], 1);
        }
    } else if (b < KB_WUC) {
        int i = (b - KB_CC) * 256 + t;  // < 49152 exact
        Wuc[i] = f2bf(ldraw(Wu_r, i, fp32));
    } else if (b < KB_WET) {
        int i = (b - KB_WUC) * 256 + t;  // < 8192
        int w = i >> 6, kk = i & 63;
        float v = (kk < 48) ? ldraw(Wenc_r, kk * 128 + w, fp32) : 0.f;
        Wet[i] = f2bf(v);
    } else if (b < KB_BC) {
        if (t < 128) {
            float acc = ldraw(bu_r, t, fp32);
            for (int j = 0; j < 128; j++)
                acc += ldraw(bm_r, j, fp32) * ldraw(Wu_r, (128 + j) * 128 + t, fp32);
            bc[t] = acc;
        } else {
            bcenc[t - 128] = ldraw(benc_r, t - 128, fp32);
            buc[t - 128] = f2bf(ldraw(bu_r, t - 128, fp32));
        }
    } else {
        int i = (b - KB_BC) * 256 + t;
        if (i < 384) trc[i] = f2bf(ldraw(tr_r, i, fp32));
    }
}

// ====== K3: deg block-scan (0..97) + cluster exclusive scan (98) ======
__global__ void k_scan_a2(const int* __restrict__ deg, int* __restrict__ rowptr,
                          int* __restrict__ bsum, const int* __restrict__ ccount,
                          int* __restrict__ coff, int* __restrict__ ccur) {
    __shared__ int sd[1024];
    int t = threadIdx.x;
    if (blockIdx.x < SCAN_B) {
        int i = blockIdx.x * 1024 + t;
        int v = (i < N_NODES) ? deg[i] : 0;
        sd[t] = v;
        __syncthreads();
#pragma unroll
        for (int off = 1; off < 1024; off <<= 1) {
            int u = (t >= off) ? sd[t - off] : 0;
            __syncthreads();
            sd[t] += u;
            __syncthreads();
        }
        if (i < N_NODES) rowptr[i] = sd[t] - v;
        if (t == 1023) bsum[blockIdx.x] = sd[t];
    } else {
        int v = (t < NBC) ? ccount[t] : 0;
        sd[t] = v;
        __syncthreads();
#pragma unroll
        for (int off = 1; off < 1024; off <<= 1) {
            int u = (t >= off) ? sd[t - off] : 0;
            __syncthreads();
            sd[t] += u;
            __syncthreads();
        }
        if (t < NBC) {
            int ex = sd[t] - v;
            coff[t] = ex;
            ccur[t] = ex;
            if (t == NBC - 1) coff[NBC] = sd[t];
        }
    }
}

// ====== K4: apply block offsets to rowptr (each block sums bsum prefix itself) ===
__global__ void k_scan_c2(int* __restrict__ rowptr, const int* __restrict__ bsum) {
    __shared__ int sb[128];
    __shared__ int offs;
    int b = blockIdx.x, t = threadIdx.x;
    if (t < 128) sb[t] = (t < b) ? bsum[t] : 0;   // b <= 97 < 128
    __syncthreads();
    if (t == 0) {
        int s = 0;
        for (int k = 0; k < 128; k++) s += sb[k];
        offs = s;
    }
    __syncthreads();
    int i = b * 1024 + t;
    if (i < N_NODES) rowptr[i] = rowptr[i] + offs;
    if (b == 0 && t == 0) rowptr[N_NODES] = N_EDGES;
}

// == K5: encoder MFMA + CSR fill (pass C, LDS cursors) + cluster fill + deg0 list ==
#define K5_EN 1563
#define K5_PC (K5_EN + SCAN_B)   // 1661
#define K5_CF (K5_PC + SCAN_B)   // 1759
#define K5_L0 (K5_CF + 391)      // 2150
__global__ void k_front(const bf16* __restrict__ xin, const bf16* __restrict__ Wet,
                        const float* __restrict__ bcenc, bf16* __restrict__ xb,
                        const int* __restrict__ rowptr, const int* __restrict__ ebuf,
                        int* __restrict__ colx, const int* __restrict__ ccc,
                        int* __restrict__ ccur, int* __restrict__ cnodes,
                        const int* __restrict__ deg, int* __restrict__ n0list,
                        int* __restrict__ n0cnt) {
    __shared__ int cur[1024];
    __shared__ int h[NBC], cb[NBC];
    int b = blockIdx.x;
    if (b >= K5_EN) {
        if (b < K5_PC) {
            // ---- pass C: scatter bucket's edges into CSR window via LDS cursors
            int bb = b - K5_EN;
            int base = bb << 10;
            int nlim = min(1024, N_NODES - base);
            for (int i = threadIdx.x; i < nlim; i += 256) cur[i] = rowptr[base + i];
            __syncthreads();
            int cnt = rowptr[base + nlim] - rowptr[base];
            const int* eb = ebuf + bb * CAPB;
            for (int e = threadIdx.x; e < cnt; e += 256) {
                int v = eb[e];
                int p = atomicAdd(&cur[v & 1023], 1);
                colx[p] = v >> 10;
            }
        } else if (b < K5_CF) {
            // ---- cluster-node fill via LDS histogram + chunk reservation
            int bb = b - K5_PC;
            int base = bb << 10;
            int nlim = min(1024, N_NODES - base);
            for (int j = threadIdx.x; j < NBC; j += 256) h[j] = 0;
            __syncthreads();
            int cls[4];
#pragma unroll
            for (int k = 0; k < 4; k++) {
                int li = k * 256 + threadIdx.x;
                cls[k] = (li < nlim) ? ccc[base + li] : -1;
                if (cls[k] >= 0) atomicAdd(&h[cls[k]], 1);
            }
            __syncthreads();
            for (int j = threadIdx.x; j < NBC; j += 256) {
                cb[j] = h[j] ? atomicAdd(&ccur[j], h[j]) : 0;
                h[j] = 0;
            }
            __syncthreads();
#pragma unroll
            for (int k = 0; k < 4; k++) {
                if (cls[k] >= 0) {
                    int p = cb[cls[k]] + atomicAdd(&h[cls[k]], 1);
                    cnodes[p] = base + k * 256 + threadIdx.x;
                }
            }
        } else {
            // ---- deg-0 list
            int i = (b - K5_CF) * 256 + threadIdx.x;
            if (i < N_NODES && deg[i] == 0) {
                int p = atomicAdd(n0cnt, 1);
                if (p < MAXFIX) n0list[p] = i;
            }
        }
        return;
    }
    // ---- MFMA encoder: xb = bf16( xin[N,64] @ Wet^T + benc ) ----
    int tid = threadIdx.x;
    int r0 = b * 64;
    int wave = tid >> 6, lane = tid & 63, quad = lane >> 4, nidx = lane & 15;
    int colbase = wave * 32;

    int arow[4];
#pragma unroll
    for (int rt = 0; rt < 4; rt++) {
        int gr = r0 + rt * 16 + nidx;
        arow[rt] = (gr < N_NODES) ? gr : (N_NODES - 1);
    }
    f4v acc[4][2];
#pragma unroll
    for (int rt = 0; rt < 4; rt++)
#pragma unroll
        for (int ct = 0; ct < 2; ct++) acc[rt][ct] = (f4v){0.f, 0.f, 0.f, 0.f};

#pragma unroll
    for (int s = 0; s < 2; s++) {
        int k0 = s * 32;
        s8v bfrag[4];
#pragma unroll
        for (int rt = 0; rt < 4; rt++)
            bfrag[rt] = *(const s8v*)((const short*)xin + (size_t)arow[rt] * 64 + k0 + quad * 8);
#pragma unroll
        for (int ct = 0; ct < 2; ct++) {
            s8v wfr = *(const s8v*)((const short*)Wet + (colbase + ct * 16 + nidx) * 64 + k0 + quad * 8);
#pragma unroll
            for (int rt = 0; rt < 4; rt++)
                acc[rt][ct] = __builtin_amdgcn_mfma_f32_16x16x32_bf16(wfr, bfrag[rt], acc[rt][ct], 0, 0, 0);
        }
    }
#pragma unroll
    for (int rt = 0; rt < 4; rt++) {
        int gr = r0 + rt * 16 + nidx;
        if (gr < N_NODES) {
#pragma unroll
            for (int ct = 0; ct < 2; ct++) {
                int wc0 = colbase + ct * 16 + quad * 4;
                f4v bv = *(const f4v*)(bcenc + wc0);
                size_t idx = (size_t)gr * HD + wc0;
                s4v ob;
#pragma unroll
                for (int r = 0; r < 4; r++) {
                    float nv = acc[rt][ct][r] + bv[r];
                    bf16 h2 = f2bf(nv);
                    ob[r] = *(short*)&h2;
                }
                *(s4v*)((short*)xb + idx) = ob;
            }
        }
    }
}

// ====== K6 (per layer): cluster pooling (blocks 0..383) + edge aggregation =======
__global__ void k_aggpool(const bf16* __restrict__ xb, const int* __restrict__ rowptr,
                          const int* __restrict__ colx, bf16* __restrict__ mb,
                          const int* __restrict__ coff, const int* __restrict__ cnodes,
                          const bf16* __restrict__ trc, bf16* __restrict__ pooled) {
    __shared__ float red[8][128];
    int tid = threadIdx.x;
    if (blockIdx.x < NBC) {
        int cl = blockIdx.x;
        int lo = coff[cl], hi = coff[cl + 1];
        int cnt = hi - lo;
        int slot = tid >> 5, cg = tid & 31;
        float a0 = 0.f, a1 = 0.f, a2 = 0.f, a3 = 0.f;
        for (int i = lo + slot; i < hi; i += 8) {
            int nd = cnodes[i];
            s4v v = *(const s4v*)((const short*)xb + (size_t)nd * HD + cg * 4);
            a0 += sh2f(v[0]); a1 += sh2f(v[1]); a2 += sh2f(v[2]); a3 += sh2f(v[3]);
        }
        red[slot][cg * 4 + 0] = a0;
        red[slot][cg * 4 + 1] = a1;
        red[slot][cg * 4 + 2] = a2;
        red[slot][cg * 4 + 3] = a3;
        __syncthreads();
        if (tid < 128) {
            float s = 0.f;
#pragma unroll
            for (int k = 0; k < 8; k++) s += red[k][tid];
            float v = s / (float)(cnt > 1 ? cnt : 1) * bf2f(trc[cl]);
            pooled[cl * HD + tid] = f2bf(v);
        }
        return;
    }
    // ---- aggregation: mean of x[src] over incoming edges ----
    int wave = tid >> 6, lane = tid & 63;
    int node = (blockIdx.x - NBC) * 4 + wave;
    if (node >= N_NODES) return;
    int half = lane >> 5;
    int l = lane & 31;
    int lo = rowptr[node], hi = rowptr[node + 1];
    float a0 = 0.f, a1 = 0.f, a2 = 0.f, a3 = 0.f;
    int j = lo + half;
    while (j + 2 < hi) {
        int s0 = colx[j], s1 = colx[j + 2];
        s4v v0 = *(const s4v*)((const short*)xb + (size_t)s0 * HD + l * 4);
        s4v v1 = *(const s4v*)((const short*)xb + (size_t)s1 * HD + l * 4);
        a0 += sh2f(v0[0]) + sh2f(v1[0]);
        a1 += sh2f(v0[1]) + sh2f(v1[1]);
        a2 += sh2f(v0[2]) + sh2f(v1[2]);
        a3 += sh2f(v0[3]) + sh2f(v1[3]);
        j += 4;
    }
    if (j < hi) {
        int s0 = colx[j];
        s4v v0 = *(const s4v*)((const short*)xb + (size_t)s0 * HD + l * 4);
        a0 += sh2f(v0[0]);
        a1 += sh2f(v0[1]);
        a2 += sh2f(v0[2]);
        a3 += sh2f(v0[3]);
    }
    a0 += __shfl_down(a0, 32);
    a1 += __shfl_down(a1, 32);
    a2 += __shfl_down(a2, 32);
    a3 += __shfl_down(a3, 32);
    if (half == 0) {
        int d = hi - lo;
        float inv = 1.0f / (float)(d > 1 ? d : 1);
        s4v o;
        bf16 h0 = f2bf(a0 * inv); o[0] = *(short*)&h0;
        bf16 h1 = f2bf(a1 * inv); o[1] = *(short*)&h1;
        bf16 h2 = f2bf(a2 * inv); o[2] = *(short*)&h2;
        bf16 h3 = f2bf(a3 * inv); o[3] = *(short*)&h3;
        *(s4v*)((short*)mb + (size_t)node * HD + l * 4) = o;
    }
}

// ====== K7 (per layer): fused update (persistent, LDS-staged) + deg-0 fixup ======
__global__ __launch_bounds__(256, 2) void k_fused2(
    const bf16* __restrict__ xb, const bf16* __restrict__ mb, const bf16* __restrict__ pooled,
    const bf16* __restrict__ Wc, const float* __restrict__ bc,
    const int* __restrict__ cc, const int* __restrict__ deg,
    const bf16* __restrict__ Wuc, const bf16* __restrict__ buc,
    const int* __restrict__ n0list, const int* __restrict__ n0cnt,
    bf16* __restrict__ xbo, const int* __restrict__ flags,
    void* __restrict__ out, int last) {
    __shared__ short Lx[64 * 128];
    __shared__ short Lm[64 * 128];
    __shared__ short Lp[64 * 128];
    __shared__ float fxv[128];
    __shared__ float fpv[128];
    int tid = threadIdx.x;
    int wave = tid >> 6, lane = tid & 63, quad = lane >> 4, nidx = lane & 15;
    int colbase = wave * 32;
    int fp32out = flags[0];

    s8v wfr[12][2];
#pragma unroll
    for (int ct = 0; ct < 2; ct++) {
        int wcol = colbase + ((nidx >> 2) << 3) + ct * 4 + (nidx & 3);
        const short* wrow = (const short*)Wc + (size_t)wcol * 384 + quad * 8;
#pragma unroll
        for (int s = 0; s < 12; s++) wfr[s][ct] = *(const s8v*)(wrow + s * 32);
    }
    int cb2 = colbase + quad * 8;
    f4v bv0 = *(const f4v*)(bc + cb2);
    f4v bv1 = *(const f4v*)(bc + cb2 + 4);

    int srow = lane >> 4;
    int sc = lane & 15;

    for (int t = blockIdx.x; t < TILES; t += GRID_F) {
        int r0 = t * 64;
#pragma unroll
        for (int ii = 0; ii < 4; ii++) {
            int i = wave * 4 + ii;
            int lr = i * 4 + srow;
            int gr = r0 + lr;
            int grc = (gr < N_NODES) ? gr : (N_NODES - 1);
            int gc = sc ^ (lr & 15);
            gl2lds16((const short*)xb + (size_t)grc * HD + gc * 8, (char*)Lx + i * 1024);
            gl2lds16((const short*)mb + (size_t)grc * HD + gc * 8, (char*)Lm + i * 1024);
            int ci = cc[grc];
            gl2lds16((const short*)pooled + (size_t)ci * HD + gc * 8, (char*)Lp + i * 1024);
        }
        __syncthreads();

        f4v acc[4][2];
#pragma unroll
        for (int rt = 0; rt < 4; rt++)
#pragma unroll
            for (int ct = 0; ct < 2; ct++) acc[rt][ct] = (f4v){0.f, 0.f, 0.f, 0.f};

#pragma unroll
        for (int s = 0; s < 12; s++) {
            const short* Ls = (s < 4) ? Lx : ((s < 8) ? Lm : Lp);
            int c = (s & 3) * 4 + quad;
            s8v bfrag[4];
#pragma unroll
            for (int rt = 0; rt < 4; rt++) {
                int row = rt * 16 + nidx;
                int slot = c ^ nidx;
                bfrag[rt] = *(const s8v*)(Ls + row * 128 + slot * 8);
            }
#pragma unroll
            for (int ct = 0; ct < 2; ct++)
#pragma unroll
                for (int rt = 0; rt < 4; rt++)
                    acc[rt][ct] = __builtin_amdgcn_mfma_f32_16x16x32_bf16(wfr[s][ct], bfrag[rt], acc[rt][ct], 0, 0, 0);
        }

#pragma unroll
        for (int rt = 0; rt < 4; rt++) {
            int gr = r0 + rt * 16 + nidx;
            if (gr < N_NODES && deg[gr] > 0) {
                int row = rt * 16 + nidx;
                int slot = ((colbase >> 3) + quad) ^ nidx;
                s8v xo = *(const s8v*)(Lx + row * 128 + slot * 8);
                size_t idx = (size_t)gr * HD + cb2;
                float nv[8];
#pragma unroll
                for (int r = 0; r < 4; r++) {
                    float v0 = acc[rt][0][r] + bv0[r];
                    v0 = (v0 > 0.f) ? v0 : 0.01f * v0;
                    nv[r] = sh2f(xo[r]) + v0;
                    float v1 = acc[rt][1][r] + bv1[r];
                    v1 = (v1 > 0.f) ? v1 : 0.01f * v1;
                    nv[4 + r] = sh2f(xo[4 + r]) + v1;
                }
                if (last) {
                    if (fp32out) {
                        f4v o0 = {nv[0], nv[1], nv[2], nv[3]};
                        f4v o1 = {nv[4], nv[5], nv[6], nv[7]};
                        *(f4v*)((float*)out + idx) = o0;
                        *(f4v*)((float*)out + idx + 4) = o1;
                    } else {
                        s8v ob;
#pragma unroll
                        for (int r = 0; r < 8; r++) { bf16 h = f2bf(nv[r]); ob[r] = *(short*)&h; }
                        *(s8v*)((short*)out + idx) = ob;
                    }
                } else {
                    s8v ob;
#pragma unroll
                    for (int r = 0; r < 8; r++) { bf16 h = f2bf(nv[r]); ob[r] = *(short*)&h; }
                    *(s8v*)((short*)xbo + idx) = ob;
                }
            }
        }
        __syncthreads();
    }

    // ---- deg-0 fixup tail (disjoint rows; fused2 skipped deg==0) ----
    int cnt0 = *n0cnt;
    if (cnt0 > MAXFIX) cnt0 = MAXFIX;
    for (int j = blockIdx.x; j < cnt0; j += gridDim.x) {
        int v = n0list[j];
        if (tid < 128) {
            fxv[tid] = bf2f(xb[(size_t)v * HD + tid]);
            fpv[tid] = bf2f(pooled[cc[v] * HD + tid]);
        }
        __syncthreads();
        if (tid < 128) {
            float acc = bf2f(buc[tid]);
            for (int k = 0; k < 128; k++)
                acc += fxv[k] * bf2f(Wuc[k * 128 + tid]) + fpv[k] * bf2f(Wuc[(256 + k) * 128 + tid]);
            float u = acc > 0.f ? acc : 0.01f * acc;
            size_t idx = (size_t)v * HD + tid;
            float nv = fxv[tid] + u;
            if (last) {
                if (fp32out) ((float*)out)[idx] = nv;
                else ((bf16*)out)[idx] = f2bf(nv);
            } else {
                xbo[idx] = f2bf(nv);
            }
        }
        __syncthreads();
    }
}

extern "C" void kernel_launch(void* const* d_in, const int* in_sizes, int n_in,
                              void* d_out, int out_size, void* d_ws, size_t ws_size,
                              hipStream_t stream) {
    const void* cf_r = d_in[0];
    const void* slf_r = d_in[1];
    const void* z_r = d_in[2];
    const void* tr_r = d_in[3];
    const void* Wenc_r = d_in[4];
    const void* benc_r = d_in[5];
    const void* Wm_r = d_in[6];
    const void* bm_r = d_in[7];
    const void* Wu_r = d_in[8];
    const void* bu_r = d_in[9];
    const int* e_r = (const int*)d_in[10];
    const int* cc_r = (const int*)d_in[11];

    char* w = (char*)d_ws;
    auto alloc = [&](size_t bytes) -> char* {
        char* p = w;
        w += (bytes + 63) & ~(size_t)63;
        return p;
    };
    bf16* xb0 = (bf16*)alloc((size_t)N_NODES * HD * 2);
    bf16* xb1 = (bf16*)alloc((size_t)N_NODES * HD * 2);
    bf16* mb = (bf16*)alloc((size_t)N_NODES * HD * 2);
    bf16* xin = (bf16*)alloc((size_t)N_NODES * 64 * 2);
    bf16* Wc = (bf16*)alloc(128 * 384 * 2);
    float* bc = (float*)alloc(128 * 4);
    bf16* Wet = (bf16*)alloc(128 * 64 * 2);
    float* bcenc = (float*)alloc(128 * 4);
    bf16* pooled = (bf16*)alloc(NBC * HD * 2);
    int* deg = (int*)alloc(N_NODES * 4);
    int* rowptr = (int*)alloc((N_NODES + 1) * 4);
    int* colx = (int*)alloc(N_EDGES * 4);
    int* ccount = (int*)alloc(NBC * 4);
    int* coff = (int*)alloc((NBC + 1) * 4);
    int* ccur = (int*)alloc(NBC * 4);
    int* cnodes = (int*)alloc(N_NODES * 4);
    int* flags = (int*)alloc(64);
    int* bsum = (int*)alloc(SCAN_B * 4);
    int* n0list = (int*)alloc(MAXFIX * 4);
    int* n0cnt = (int*)alloc(64);
    bf16* trc = (bf16*)alloc(384 * 2);
    bf16* Wuc = (bf16*)alloc(49152 * 2);
    bf16* buc = (bf16*)alloc(128 * 2);
    int* ccc = (int*)alloc(N_NODES * 4);
    int* bcur = (int*)alloc(SCAN_B * 4);
    int* ebuf = (int*)alloc((size_t)SCAN_B * CAPB * 4);   // 6.4 MB

    // 1) detect dtypes + zero counters
    k_init<<<100, 256, 0, stream>>>((const unsigned short*)Wenc_r, e_r, flags,
                                    deg, ccount, n0cnt, bcur);
    // 2) conversions + edge binning + counts + weight composition
    k_mega<<<KB_TR, 256, 0, stream>>>(flags, cf_r, slf_r, z_r, tr_r, Wenc_r, benc_r,
                                      Wm_r, bm_r, Wu_r, bu_r, e_r, cc_r,
                                      xin, trc, Wuc, buc, ccc, deg, ccount,
                                      Wc, bc, Wet, bcenc, bcur, ebuf);
    // 3) deg block-scans + cluster scan
    k_scan_a2<<<SCAN_B + 1, 1024, 0, stream>>>(deg, rowptr, bsum, ccount, coff, ccur);
    // 4) finalize rowptr
    k_scan_c2<<<SCAN_B, 1024, 0, stream>>>(rowptr, bsum);
    // 5) encoder + CSR fill (pass C) + cluster fill + deg-0 list
    k_front<<<K5_L0, 256, 0, stream>>>(xin, Wet, bcenc, xb0,
                                       rowptr, ebuf, colx, ccc, ccur, cnodes,
                                       deg, n0list, n0cnt);

    bf16* xbufs[2] = {xb0, xb1};
    for (int layer = 0; layer < 3; layer++) {
        bf16* xbi = xbufs[layer & 1];
        bf16* xbo = xbufs[(layer + 1) & 1];
        int last = (layer == 2);
        k_aggpool<<<AGG_B + NBC, 256, 0, stream>>>(xbi, rowptr, colx, mb,
                                                   coff, cnodes, trc, pooled);
        k_fused2<<<GRID_F, 256, 0, stream>>>(xbi, mb, pooled, Wc, bc, ccc, deg,
                                             Wuc, buc, n0list, n0cnt,
                                             xbo, flags, d_out, last);
    }
}